// Round 8
// baseline (853.667 us; speedup 1.0000x reference)
//
#include <hip/hip_runtime.h>

#define THRESH 0.1f

typedef float f4 __attribute__((ext_vector_type(4)));
typedef float f2 __attribute__((ext_vector_type(2)));

// ---------------------------------------------------------------------------
// Merged weight norm (per-row math identical to all prior rounds -> same bits).
// ---------------------------------------------------------------------------
__global__ void wnorm_all(const float* __restrict__ c0v, const float* __restrict__ c0g,
                          const float* __restrict__ c1v, const float* __restrict__ c1g,
                          const float* __restrict__ c2v, const float* __restrict__ c2g,
                          const float* __restrict__ c3v, const float* __restrict__ c3g,
                          const float* __restrict__ lv,  const float* __restrict__ lg,
                          float* __restrict__ w0, float* __restrict__ w1,
                          float* __restrict__ w2, float* __restrict__ w3,
                          float* __restrict__ wl) {
    int rb = blockIdx.x;
    const float *v, *g; float* w; int fanin, row;
    if (rb < 8)        { v = c0v; g = c0g; w = w0; fanin = 18;   row = rb; }
    else if (rb < 24)  { v = c1v; g = c1g; w = w1; fanin = 72;   row = rb - 8; }
    else if (rb < 56)  { v = c2v; g = c2g; w = w2; fanin = 144;  row = rb - 24; }
    else if (rb < 120) { v = c3v; g = c3g; w = w3; fanin = 288;  row = rb - 56; }
    else               { v = lv;  g = lg;  w = wl; fanin = 1024; row = rb - 120; }

    const float* vr = v + (size_t)row * fanin;
    float ss = 0.f;
    for (int i = threadIdx.x; i < fanin; i += 64) { float x = vr[i]; ss = fmaf(x, x, ss); }
    #pragma unroll
    for (int off = 32; off > 0; off >>= 1) ss += __shfl_down(ss, off);
    ss = __shfl(ss, 0);
    float scale = g[row] / sqrtf(ss);
    float* wr = w + (size_t)row * fanin;
    for (int i = threadIdx.x; i < fanin; i += 64) wr[i] = vr[i] * scale;
}

// ---------------------------------------------------------------------------
// Fused conv3x3(SAME) + IAF + 2x2 avgpool — WAVE-PRIVATE LDS, BARRIER-FREE.
// One 64-thread block = one wave = WY rows x WX cols of conv pixels x CG c_outs.
// The wave stages its own (strip+halo) frame slab (double-buffered) and reads
// only its own writes -> same-wave DS ordering makes __syncthreads unnecessary.
// Pipeline per t: stage(t+1 from pf regs) -> issue global gather(t+2 into pf)
// -> compute t from slab -> spike/pool/store. No sync anywhere in the T loop.
// LDS layout [row][col][ci] with odd quad-stride CIP -> conflict-free b128.
// Per-(pixel,c_out) fmaf order (ci asc, k asc), staged values, and pool
// association (s0+s1)+(s2+s3) identical to rounds 3-7 -> bitwise-identical.
// ---------------------------------------------------------------------------
template<int CIN, int H, int COUT, int CG, int WX, int CIP>
__launch_bounds__(64)
__global__ void conv_iaf_pool(const float* __restrict__ in, const float* __restrict__ w,
                              float* __restrict__ out, int B, int T) {
    constexpr int Hp    = H / 2;
    constexpr int PP    = Hp * Hp;
    constexpr int HH    = H * H;
    constexpr int WY    = 64 / WX;           // conv rows per wave
    constexpr int XW    = H / WX;            // waves across x (L0: 2, else 1)
    constexpr int STRIPS= H / WY;            // waves down y
    constexpr int CGRP  = COUT / CG;
    constexpr int SCOLS = WX + 2;            // slab cols (with halo)
    constexpr int SR    = WY + 2;            // slab rows (with halo)
    constexpr int SLABN = SR * SCOLS * CIP;
    constexpr bool QUAD = (CIN % 4 == 0);
    constexpr int CPW   = QUAD ? 4 : 2;      // channels per staged vector
    constexpr int NCQ   = CIN / CPW;
    // staging geometry
    constexpr bool FULLY = (WY == H);        // wave covers whole frame (L3)
    constexpr int SCN   = (XW == 1) ? WX : (WX + 2);
    constexpr int R0    = FULLY ? 1 : 0;
    constexpr int NRR   = FULLY ? H : SR;
    constexpr int NU    = NRR * SCN * NCQ;   // staging vector units per t
    constexpr int UN    = (NU + 63) / 64;
    constexpr bool GUARD = !(FULLY && (NU % 64 == 0));

    __shared__ alignas(16) float slab[2][SLABN];

    const int l = threadIdx.x;

    // XCD swizzle: same-b waves cluster on one XCD (assignment ~ bx % 8)
    const int G  = gridDim.x, bx = blockIdx.x;
    const int p  = (bx & 7) * (G >> 3) + (bx >> 3);
    constexpr int PER_B = CGRP * STRIPS * XW;
    const int b  = p / PER_B;
    const int r_ = p % PER_B;
    const int cg = r_ / (STRIPS * XW);
    const int sy = (r_ % (STRIPS * XW)) / XW;
    const int sx = r_ % XW;

    const int xl = l % WX, ylw = l / WX;
    const int x0 = sx * WX, y0 = sy * WY;
    const int x  = x0 + xl, y = y0 + ylw;

    const int c0 = cg * CG;
    const float* __restrict__ wu = w + (size_t)c0 * (CIN * 9);

    // ---- staging unit maps (lane-invariant over t) ----
    int goff[UN], loff[UN];
    #pragma unroll
    for (int i = 0; i < UN; ++i) {
        const int idx = l + i * 64;
        const int j    = idx % SCN;
        const int ridx = (idx / SCN) % NRR;
        const int cq   = idx / (SCN * NRR);
        const int rr   = R0 + ridx;
        const int sc   = (XW == 1) ? (1 + j) : j;
        const int gx   = (XW == 1) ? j : (x0 - 1 + j);
        const int gy   = y0 - 1 + rr;
        const bool ok  = (idx < NU) && ((unsigned)gy < (unsigned)H) &&
                         ((unsigned)gx < (unsigned)H);
        goff[i] = ok ? (cq * CPW * HH + gy * H + gx) : -1;
        loff[i] = ok ? ((rr * SCOLS + sc) * CIP + cq * CPW) : -1;
    }

    // ---- weights resident in VGPRs when small (L0 only) ----
    constexpr bool WREG = (CG * CIN * 9) <= 80;
    float wreg[WREG ? (CG * CIN * 9) : 1];
    if constexpr (WREG) {
        #pragma unroll
        for (int i = 0; i < CG * CIN * 9; ++i) wreg[i] = wu[i];
    }

    // zero both slabs once (halo cells persist as zeros; wave-private -> no sync)
    for (int i = l; i < 2 * SLABN; i += 64) (&slab[0][0])[i] = 0.f;

    const int baseoff = (ylw * SCOLS + xl) * CIP;   // patch base (words)

    float vmem[CG];
    #pragma unroll
    for (int c = 0; c < CG; ++c) vmem[c] = 0.f;

    f4 pf[UN];
    #define GATHER(inb)                                                          \
        _Pragma("unroll")                                                        \
        for (int i = 0; i < UN; ++i) {                                           \
            f4 r{0.f, 0.f, 0.f, 0.f};                                            \
            if (!GUARD || goff[i] >= 0) {                                        \
                const int g_ = goff[i];                                          \
                r.x = (inb)[g_]; r.y = (inb)[g_ + HH];                           \
                if constexpr (QUAD) { r.z = (inb)[g_ + 2 * HH];                  \
                                      r.w = (inb)[g_ + 3 * HH]; }                \
            }                                                                    \
            pf[i] = r;                                                           \
        }
    #define STAGE(buf)                                                           \
        _Pragma("unroll")                                                        \
        for (int i = 0; i < UN; ++i) {                                           \
            if (!GUARD || loff[i] >= 0) {                                        \
                if constexpr (QUAD) *(f4*)(&slab[buf][loff[i]]) = pf[i];         \
                else { f2 v2{pf[i].x, pf[i].y};                                  \
                       *(f2*)(&slab[buf][loff[i]]) = v2; }                       \
            }                                                                    \
        }

    {   // prologue: stage frame 0, prefetch frame 1 (wave-private, no sync)
        const float* inb0 = in + (size_t)(b * T) * (CIN * HH);
        GATHER(inb0)
        STAGE(0)
        const float* inb1 = in + (size_t)(b * T + 1) * (CIN * HH);
        GATHER(inb1)
    }

    for (int t = 0; t < T; ++t) {
        if (t + 1 < T) { STAGE((t + 1) & 1) }
        if (t + 2 < T) {
            const float* inb = in + (size_t)(b * T + t + 2) * (CIN * HH);
            GATHER(inb)
        }

        const float* sl = &slab[t & 1][0] + baseoff;
        float acc[CG];
        #pragma unroll
        for (int c = 0; c < CG; ++c) acc[c] = 0.f;

        if constexpr (QUAD) {
            #pragma unroll
            for (int cq = 0; cq < NCQ; ++cq) {
                f4 P[9];
                #pragma unroll
                for (int k = 0; k < 9; ++k)
                    P[k] = *(const f4*)(sl + ((k / 3) * SCOLS + (k % 3)) * CIP + 4 * cq);
                #pragma unroll
                for (int cid = 0; cid < 4; ++cid) {
                    const int ci = cq * 4 + cid;
                    #pragma unroll
                    for (int c = 0; c < CG; ++c)
                        #pragma unroll
                        for (int k = 0; k < 9; ++k)
                            acc[c] = fmaf(P[k][cid],
                                          WREG ? wreg[(c * CIN + ci) * 9 + k]
                                               : wu[(size_t)(c * CIN + ci) * 9 + k],
                                          acc[c]);
                }
            }
        } else {
            f2 P[9];
            #pragma unroll
            for (int k = 0; k < 9; ++k)
                P[k] = *(const f2*)(sl + ((k / 3) * SCOLS + (k % 3)) * CIP);
            #pragma unroll
            for (int cid = 0; cid < 2; ++cid)
                #pragma unroll
                for (int c = 0; c < CG; ++c)
                    #pragma unroll
                    for (int k = 0; k < 9; ++k)
                        acc[c] = fmaf(P[k][cid],
                                      WREG ? wreg[(c * CIN + cid) * 9 + k]
                                           : wu[(size_t)(c * CIN + cid) * 9 + k],
                                      acc[c]);
        }

        #pragma unroll
        for (int c = 0; c < CG; ++c) {
            vmem[c] += acc[c];
            float s = (vmem[c] >= THRESH) ? 1.f : 0.f;
            vmem[c] -= THRESH * s;
            float sum = s;                         // exact 0/1 sums
            sum += __shfl_xor(sum, 1);             // (s0+s1)
            sum += __shfl_xor(sum, WX);            // + (s2+s3)
            if (((xl | ylw) & 1) == 0)
                out[((size_t)(b * T + t) * COUT + (c0 + c)) * PP + (y >> 1) * Hp + (x >> 1)]
                    = 0.25f * sum;
        }
    }
    #undef GATHER
    #undef STAGE
}

// ---------------------------------------------------------------------------
// Linear: out (1600, 11) = h (1600, 1024) @ w^T (11, 1024)
// ---------------------------------------------------------------------------
__global__ void linear_kernel(const float* __restrict__ h, const float* __restrict__ w,
                              float* __restrict__ out) {
    __shared__ float hs[1024];
    __shared__ float part[16][17];
    const int n = blockIdx.x;
    for (int i = threadIdx.x; i < 1024; i += blockDim.x)
        hs[i] = h[(size_t)n * 1024 + i];
    __syncthreads();
    const int j = threadIdx.x & 15, ch = threadIdx.x >> 4;
    float acc = 0.f;
    if (j < 11) {
        const float* wr = w + (size_t)j * 1024 + ch * 64;
        const float* hh = hs + ch * 64;
        #pragma unroll 8
        for (int k = 0; k < 64; ++k) acc = fmaf(hh[k], wr[k], acc);
    }
    part[j][ch] = acc;
    __syncthreads();
    if (threadIdx.x < 11) {
        float s = 0.f;
        #pragma unroll
        for (int cc = 0; cc < 16; ++cc) s += part[threadIdx.x][cc];
        out[(size_t)n * 11 + threadIdx.x] = s;
    }
}

// ---------------------------------------------------------------------------
extern "C" void kernel_launch(void* const* d_in, const int* in_sizes, int n_in,
                              void* d_out, int out_size, void* d_ws, size_t ws_size,
                              hipStream_t stream) {
    const int B = 32, T = 50;

    const float* x   = (const float*)d_in[0];
    const float* c0v = (const float*)d_in[1];
    const float* c0g = (const float*)d_in[2];
    const float* c1v = (const float*)d_in[3];
    const float* c1g = (const float*)d_in[4];
    const float* c2v = (const float*)d_in[5];
    const float* c2g = (const float*)d_in[6];
    const float* c3v = (const float*)d_in[7];
    const float* c3g = (const float*)d_in[8];
    const float* lv  = (const float*)d_in[9];
    const float* lg  = (const float*)d_in[10];
    float* out = (float*)d_out;

    // Workspace layout (floats)
    float* ws = (float*)d_ws;
    float* w0 = ws;                    // 8*2*9     = 144
    float* w1 = w0 + 144;              // 16*8*9    = 1152
    float* w2 = w1 + 1152;             // 32*16*9   = 4608
    float* w3 = w2 + 4608;             // 64*32*9   = 18432
    float* wl = w3 + 18432;            // 11*1024   = 11264
    float* bufA = ws + 40960;                  // L0 out: 1600*8*32*32  = 13,107,200
    float* bufB = bufA + (size_t)13107200;     // L1 out: 1600*16*16*16 =  6,553,600
    // L2 out (3,276,800) reuses bufA; L3 out (1,638,400) reuses bufB.

    wnorm_all<<<131, 64, 0, stream>>>(c0v, c0g, c1v, c1g, c2v, c2g, c3v, c3g,
                                      lv, lg, w0, w1, w2, w3, wl);

    // <CIN,H,COUT,CG,WX,CIP>; 64-thread blocks, one wave-private slab each.
    // grid = B * CGRP * STRIPS * XW
    conv_iaf_pool<2,  64, 8,  4, 32, 2 ><<<4096, 64, 0, stream>>>(x,    w0, bufA, B, T); // L0
    conv_iaf_pool<8,  32, 16, 4, 32, 12><<<2048, 64, 0, stream>>>(bufA, w1, bufB, B, T); // L1
    conv_iaf_pool<16, 16, 32, 4, 16, 20><<<1024, 64, 0, stream>>>(bufB, w2, bufA, B, T); // L2
    conv_iaf_pool<32, 8,  64, 4, 8,  36><<<512,  64, 0, stream>>>(bufA, w3, bufB, B, T); // L3

    linear_kernel<<<B * T, 256, 0, stream>>>(bufB, wl, out);
}

// Round 9
// 676.236 us; speedup vs baseline: 1.2624x; 1.2624x over previous
//
#include <hip/hip_runtime.h>

#define THRESH 0.1f

typedef float f4 __attribute__((ext_vector_type(4)));
typedef float f2 __attribute__((ext_vector_type(2)));

// ---------------------------------------------------------------------------
// Merged weight norm (per-row math identical to all prior rounds -> same bits).
// rows [0,8): conv0, [8,24): conv1, [24,56): conv2, [56,120): conv3, [120,131): lin
// ---------------------------------------------------------------------------
__global__ void wnorm_all(const float* __restrict__ c0v, const float* __restrict__ c0g,
                          const float* __restrict__ c1v, const float* __restrict__ c1g,
                          const float* __restrict__ c2v, const float* __restrict__ c2g,
                          const float* __restrict__ c3v, const float* __restrict__ c3g,
                          const float* __restrict__ lv,  const float* __restrict__ lg,
                          float* __restrict__ w0, float* __restrict__ w1,
                          float* __restrict__ w2, float* __restrict__ w3,
                          float* __restrict__ wl) {
    int rb = blockIdx.x;
    const float *v, *g; float* w; int fanin, row;
    if (rb < 8)        { v = c0v; g = c0g; w = w0; fanin = 18;   row = rb; }
    else if (rb < 24)  { v = c1v; g = c1g; w = w1; fanin = 72;   row = rb - 8; }
    else if (rb < 56)  { v = c2v; g = c2g; w = w2; fanin = 144;  row = rb - 24; }
    else if (rb < 120) { v = c3v; g = c3g; w = w3; fanin = 288;  row = rb - 56; }
    else               { v = lv;  g = lg;  w = wl; fanin = 1024; row = rb - 120; }

    const float* vr = v + (size_t)row * fanin;
    float ss = 0.f;
    for (int i = threadIdx.x; i < fanin; i += 64) { float x = vr[i]; ss = fmaf(x, x, ss); }
    #pragma unroll
    for (int off = 32; off > 0; off >>= 1) ss += __shfl_down(ss, off);
    ss = __shfl(ss, 0);
    float scale = g[row] / sqrtf(ss);
    float* wr = w + (size_t)row * fanin;
    for (int i = threadIdx.x; i < fanin; i += 64) wr[i] = vr[i] * scale;
}

// ---------------------------------------------------------------------------
// Fused conv3x3(SAME) + IAF + 2x2 avgpool.  (Round-7 champion structure.)
// Row-major lane->pixel map (wave = WY rows x WX cols); pool partners l^1/l^WX
// with the same (s0+s1)+(s2+s3) association as prior rounds (bitwise ident).
// LDS layout [staged_row][staged_col][ci] with CIP odd-quad-stride. Staging:
// coalesced per-ci b32 global loads -> b128/b64 LDS writes; double-buffered,
// t+2 register prefetch, one barrier per timestep. Per-(pixel,c_out) fmaf
// order is (ci ascending, k ascending) — identical to rounds 3-8.
// ---------------------------------------------------------------------------
template<int CIN, int H, int COUT, int CG, int WX, int SEGS, int BDIM, int CIP>
__launch_bounds__(BDIM)
__global__ void conv_iaf_pool(const float* __restrict__ in, const float* __restrict__ w,
                              float* __restrict__ out, int B, int T) {
    constexpr int Hp   = H / 2;
    constexpr int PP   = Hp * Hp;
    constexpr int HH   = H * H;
    constexpr int WY   = 64 / WX;          // rows per wave
    constexpr int NW   = BDIM / 64;
    constexpr int NWps = NW / SEGS;        // waves per c-group
    constexpr int XW   = H / WX;           // waves across x (L0: 2, else 1)
    constexpr int YWV  = NWps / XW;        // waves down
    constexpr int RPB  = YWV * WY;         // conv rows per block
    constexpr int STRIPS = H / RPB;
    constexpr int CGRP = COUT / (CG * SEGS);
    constexpr int SR   = RPB + 2;          // staged rows (with halo)
    constexpr int COLS = H + 2;            // staged cols (with halo)
    constexpr int SLABN = SR * COLS * CIP;
    constexpr int R0   = (RPB == H) ? 1 : 0;   // whole-frame: skip zero rows
    constexpr int NR   = (RPB == H) ? H : SR;  // staged-row iteration count
    constexpr bool QUAD = (CIN % 4 == 0);
    constexpr int CPW  = QUAD ? 4 : 2;     // channels per staged vector
    constexpr int NCQ  = CIN / CPW;
    constexpr int NU   = NR * H * NCQ;     // staging vector units per t
    constexpr int ITERS = (NU + BDIM - 1) / BDIM;

    __shared__ alignas(16) float slab[2][SLABN];

    const int tid = threadIdx.x;
    const int G = gridDim.x, bx = blockIdx.x;
    const int pb = (bx & 7) * (G >> 3) + (bx >> 3);   // XCD clustering
    const int cgb   = pb % CGRP;
    const int strip = (pb / CGRP) % STRIPS;
    const int b     = pb / (CGRP * STRIPS);

    const int wid = tid >> 6, l = tid & 63;
    const int seg = wid / NWps;
    const int wl  = wid % NWps;
    const int xw = wl % XW, yw = wl / XW;
    const int xl = l % WX, ylw = l / WX;
    const int x  = xw * WX + xl;
    const int yy = yw * WY + ylw;          // row within block strip
    const int y0 = strip * RPB;
    const int y  = y0 + yy;

    const int c0 = __builtin_amdgcn_readfirstlane((cgb * SEGS + seg) * CG);
    const float* __restrict__ wu = w + (size_t)c0 * (CIN * 9);

    // patch base addresses (word offsets; staged row yy+dr, staged col x+dc)
    int addrw[9];
    #pragma unroll
    for (int dr = 0; dr < 3; ++dr)
        #pragma unroll
        for (int dc = 0; dc < 3; ++dc)
            addrw[dr * 3 + dc] = ((yy + dr) * COLS + (x + dc)) * CIP;

    // staging unit maps (computed once; lane-invariant over t)
    int goff[ITERS], loff[ITERS];
    #pragma unroll
    for (int i = 0; i < ITERS; ++i) {
        const int idx = tid + i * BDIM;
        const int gx  = idx % H;
        const int rr0 = (idx / H) % NR;
        const int cq  = idx / (H * NR);
        const int rr  = R0 + rr0;          // staged row index
        const int gy  = y0 - 1 + rr;       // frame row
        const bool ok = (idx < NU) && (gy >= 0) && (gy < H);
        goff[i] = ok ? (cq * CPW * HH + gy * H + gx) : -1;
        loff[i] = ok ? ((rr * COLS + (gx + 1)) * CIP + cq * CPW) : -1;
    }

    constexpr bool WREG = (CG * CIN * 9) <= 80;    // L0 only
    float wreg[WREG ? (CG * CIN * 9) : 1];
    if constexpr (WREG) {
        #pragma unroll
        for (int i = 0; i < CG * CIN * 9; ++i) wreg[i] = wu[i];
    }

    // zero both buffers (covers halo rows/cols; interior overwritten per t)
    for (int i = tid; i < 2 * SLABN; i += BDIM) (&slab[0][0])[i] = 0.f;
    __syncthreads();

    float vmem[CG];
    #pragma unroll
    for (int c = 0; c < CG; ++c) vmem[c] = 0.f;

    f4 pf[ITERS];
    #define GATHER(inb)                                                         \
        _Pragma("unroll")                                                       \
        for (int i = 0; i < ITERS; ++i) {                                       \
            const int g_ = goff[i];                                             \
            f4 r_ = {0.f, 0.f, 0.f, 0.f};                                       \
            if (g_ >= 0) {                                                      \
                r_.x = (inb)[g_]; r_.y = (inb)[g_ + HH];                        \
                if constexpr (QUAD) { r_.z = (inb)[g_ + 2*HH]; r_.w = (inb)[g_ + 3*HH]; } \
            }                                                                   \
            pf[i] = r_;                                                         \
        }
    #define STAGE(buf)                                                          \
        _Pragma("unroll")                                                       \
        for (int i = 0; i < ITERS; ++i) {                                       \
            const int lo = loff[i];                                             \
            if (lo >= 0) {                                                      \
                if constexpr (QUAD) *(f4*)(&slab[buf][lo]) = pf[i];             \
                else { f2 v2_; v2_.x = pf[i].x; v2_.y = pf[i].y;                \
                       *(f2*)(&slab[buf][lo]) = v2_; }                          \
            }                                                                   \
        }

    {   // prologue: stage frame 0, prefetch frame 1
        const float* inb0 = in + (size_t)(b * T) * (CIN * HH);
        GATHER(inb0)
        STAGE(0)
        const float* inb1 = in + (size_t)(b * T + 1) * (CIN * HH);
        GATHER(inb1)
    }
    __syncthreads();

    for (int t = 0; t < T; ++t) {
        if (t + 1 < T) { STAGE((t + 1) & 1) }
        if (t + 2 < T) {
            const float* inb = in + (size_t)(b * T + t + 2) * (CIN * HH);
            GATHER(inb)
        }

        const float* sl = &slab[t & 1][0];
        float acc[CG];
        #pragma unroll
        for (int c = 0; c < CG; ++c) acc[c] = 0.f;

        if constexpr (QUAD) {
            #pragma unroll
            for (int cq = 0; cq < NCQ; ++cq) {
                f4 P[9];
                #pragma unroll
                for (int k = 0; k < 9; ++k)
                    P[k] = *(const f4*)(sl + addrw[k] + 4 * cq);
                #pragma unroll
                for (int cid = 0; cid < 4; ++cid) {
                    const int ci = cq * 4 + cid;
                    #pragma unroll
                    for (int c = 0; c < CG; ++c)
                        #pragma unroll
                        for (int k = 0; k < 9; ++k)
                            acc[c] = fmaf(P[k][cid],
                                          WREG ? wreg[(c * CIN + ci) * 9 + k]
                                               : wu[(size_t)(c * CIN + ci) * 9 + k],
                                          acc[c]);
                }
            }
        } else {
            f2 P[9];
            #pragma unroll
            for (int k = 0; k < 9; ++k)
                P[k] = *(const f2*)(sl + addrw[k]);
            #pragma unroll
            for (int cid = 0; cid < 2; ++cid)
                #pragma unroll
                for (int c = 0; c < CG; ++c)
                    #pragma unroll
                    for (int k = 0; k < 9; ++k)
                        acc[c] = fmaf(P[k][cid],
                                      WREG ? wreg[(c * CIN + cid) * 9 + k]
                                           : wu[(size_t)(c * CIN + cid) * 9 + k],
                                      acc[c]);
        }

        #pragma unroll
        for (int c = 0; c < CG; ++c) {
            vmem[c] += acc[c];
            float s = (vmem[c] >= THRESH) ? 1.f : 0.f;
            vmem[c] -= THRESH * s;
            float sum = s;                         // exact 0/1 sums
            sum += __shfl_xor(sum, 1);             // (s0+s1)
            sum += __shfl_xor(sum, WX);            // + (s2+s3)
            if (((xl | ylw) & 1) == 0)
                out[((size_t)(b * T + t) * COUT + (c0 + c)) * PP + (y >> 1) * Hp + (x >> 1)]
                    = 0.25f * sum;
        }
        __syncthreads();                           // single barrier per timestep
    }
    #undef GATHER
    #undef STAGE
}

// ---------------------------------------------------------------------------
// Linear: out (1600, 11) = h (1600, 1024) @ w^T (11, 1024)
// ---------------------------------------------------------------------------
__global__ void linear_kernel(const float* __restrict__ h, const float* __restrict__ w,
                              float* __restrict__ out) {
    __shared__ float hs[1024];
    __shared__ float part[16][17];
    const int n = blockIdx.x;
    for (int i = threadIdx.x; i < 1024; i += blockDim.x)
        hs[i] = h[(size_t)n * 1024 + i];
    __syncthreads();
    const int j = threadIdx.x & 15, ch = threadIdx.x >> 4;
    float acc = 0.f;
    if (j < 11) {
        const float* wr = w + (size_t)j * 1024 + ch * 64;
        const float* hh = hs + ch * 64;
        #pragma unroll 8
        for (int k = 0; k < 64; ++k) acc = fmaf(hh[k], wr[k], acc);
    }
    part[j][ch] = acc;
    __syncthreads();
    if (threadIdx.x < 11) {
        float s = 0.f;
        #pragma unroll
        for (int cc = 0; cc < 16; ++cc) s += part[threadIdx.x][cc];
        out[(size_t)n * 11 + threadIdx.x] = s;
    }
}

// ---------------------------------------------------------------------------
extern "C" void kernel_launch(void* const* d_in, const int* in_sizes, int n_in,
                              void* d_out, int out_size, void* d_ws, size_t ws_size,
                              hipStream_t stream) {
    const int B = 32, T = 50;

    const float* x   = (const float*)d_in[0];
    const float* c0v = (const float*)d_in[1];
    const float* c0g = (const float*)d_in[2];
    const float* c1v = (const float*)d_in[3];
    const float* c1g = (const float*)d_in[4];
    const float* c2v = (const float*)d_in[5];
    const float* c2g = (const float*)d_in[6];
    const float* c3v = (const float*)d_in[7];
    const float* c3g = (const float*)d_in[8];
    const float* lv  = (const float*)d_in[9];
    const float* lg  = (const float*)d_in[10];
    float* out = (float*)d_out;

    // Workspace layout (floats)
    float* ws = (float*)d_ws;
    float* w0 = ws;                    // 8*2*9     = 144
    float* w1 = w0 + 144;              // 16*8*9    = 1152
    float* w2 = w1 + 1152;             // 32*16*9   = 4608
    float* w3 = w2 + 4608;             // 64*32*9   = 18432
    float* wl = w3 + 18432;            // 11*1024   = 11264
    float* bufA = ws + 40960;                  // L0 out: 1600*8*32*32  = 13,107,200
    float* bufB = bufA + (size_t)13107200;     // L1 out: 1600*16*16*16 =  6,553,600
    // L2 out (3,276,800) reuses bufA; L3 out (1,638,400) reuses bufB.

    wnorm_all<<<131, 64, 0, stream>>>(c0v, c0g, c1v, c1g, c2v, c2g, c3v, c3g,
                                      lv, lg, w0, w1, w2, w3, wl);

    // <CIN,H,COUT,CG,WX,SEGS,BDIM,CIP>  grid = B * CGRP * STRIPS
    // L3 change vs round 7: CG 2->1, SEGS 2->4, BDIM 128->256 => 2048 waves
    // (2 waves/SIMD instead of 1) — the only latency-starved layer.
    conv_iaf_pool<2,  64, 8,  4, 32, 1, 256, 2 ><<<1024, 256, 0, stream>>>(x,    w0, bufA, B, T); // L0
    conv_iaf_pool<8,  32, 16, 4, 32, 1, 256, 12><<<512,  256, 0, stream>>>(bufA, w1, bufB, B, T); // L1
    conv_iaf_pool<16, 16, 32, 2, 16, 2, 256, 20><<<512,  256, 0, stream>>>(bufB, w2, bufA, B, T); // L2
    conv_iaf_pool<32, 8,  64, 1, 8,  4, 256, 36><<<512,  256, 0, stream>>>(bufA, w3, bufB, B, T); // L3

    linear_kernel<<<B * T, 256, 0, stream>>>(bufB, wl, out);
}

// Round 10
// 551.197 us; speedup vs baseline: 1.5488x; 1.2268x over previous
//
#include <hip/hip_runtime.h>

#define THRESH 0.1f

typedef float    f4 __attribute__((ext_vector_type(4)));
typedef float    f2 __attribute__((ext_vector_type(2)));
typedef _Float16 h8 __attribute__((ext_vector_type(8)));
typedef _Float16 h4 __attribute__((ext_vector_type(4)));
typedef _Float16 h2 __attribute__((ext_vector_type(2)));

// ---------------------------------------------------------------------------
// Merged weight norm (per-row reduction math identical to all prior rounds).
// Linear rows are written PERMUTED to HWC fanin order: dst[pix*64+c]=src[c*16+pix]
// (same float values; only the linear dot's summation grouping changes, which
// is within slack — conv weights w0..w3 keep identical bits).
// ---------------------------------------------------------------------------
__global__ void wnorm_all(const float* __restrict__ c0v, const float* __restrict__ c0g,
                          const float* __restrict__ c1v, const float* __restrict__ c1g,
                          const float* __restrict__ c2v, const float* __restrict__ c2g,
                          const float* __restrict__ c3v, const float* __restrict__ c3g,
                          const float* __restrict__ lv,  const float* __restrict__ lg,
                          float* __restrict__ w0, float* __restrict__ w1,
                          float* __restrict__ w2, float* __restrict__ w3,
                          float* __restrict__ wl) {
    int rb = blockIdx.x;
    const float *v, *g; float* w; int fanin, row;
    if (rb < 8)        { v = c0v; g = c0g; w = w0; fanin = 18;   row = rb; }
    else if (rb < 24)  { v = c1v; g = c1g; w = w1; fanin = 72;   row = rb - 8; }
    else if (rb < 56)  { v = c2v; g = c2g; w = w2; fanin = 144;  row = rb - 24; }
    else if (rb < 120) { v = c3v; g = c3g; w = w3; fanin = 288;  row = rb - 56; }
    else               { v = lv;  g = lg;  w = wl; fanin = 1024; row = rb - 120; }
    const bool perm = (rb >= 120);

    const float* vr = v + (size_t)row * fanin;
    float ss = 0.f;
    for (int i = threadIdx.x; i < fanin; i += 64) { float x = vr[i]; ss = fmaf(x, x, ss); }
    #pragma unroll
    for (int off = 32; off > 0; off >>= 1) ss += __shfl_down(ss, off);
    ss = __shfl(ss, 0);
    float scale = g[row] / sqrtf(ss);
    float* wr = w + (size_t)row * fanin;
    for (int i = threadIdx.x; i < fanin; i += 64) {
        int d = perm ? (((i & 15) << 6) | (i >> 4)) : i;
        wr[d] = vr[i] * scale;
    }
}

// ---------------------------------------------------------------------------
// Fused conv3x3(SAME) + IAF + 2x2 avgpool.  Round-9 structure + f16/HWC I/O.
// Inter-layer tensors: f16, layout [b,t,pix,c] (HWC). Staged values are spike
// averages in {0,.25,.5,.75,1} — exact in f16, so (float)h reproduces the f32
// operand bit-exactly and the fmaf chain (ci asc, k asc) is bitwise-identical
// to rounds 3-9. LDS: [staged_row][staged_col][c] with PSB-byte position
// stride (16/48/80: 16B-aligned, odd quad stride -> conflict-free b128).
// L0 keeps the f32 input path (CIN=2, f2 staging), emits f16 HWC.
// Double-buffered slab, t+2 register prefetch, one barrier per timestep.
// ---------------------------------------------------------------------------
template<int CIN, int H, int COUT, int CG, int WX, int SEGS, int BDIM, int PSB>
__launch_bounds__(BDIM)
__global__ void conv_iaf_pool(const void* __restrict__ in_, const float* __restrict__ w,
                              _Float16* __restrict__ out, int B, int T) {
    constexpr bool HIN  = (CIN % 8 == 0);     // f16 HWC input path
    constexpr int Hp    = H / 2;
    constexpr int PP    = Hp * Hp;
    constexpr int HH    = H * H;
    constexpr int WY    = 64 / WX;
    constexpr int NW    = BDIM / 64;
    constexpr int NWps  = NW / SEGS;
    constexpr int XW    = H / WX;             // waves across x (L0: 2, else 1)
    constexpr int YWV   = NWps / XW;
    constexpr int RPB   = YWV * WY;           // conv rows per block
    constexpr int STRIPS= H / RPB;
    constexpr int CGRP  = COUT / (CG * SEGS);
    constexpr int SR    = RPB + 2;
    constexpr int COLS  = H + 2;
    constexpr int SLABB = SR * COLS * PSB;    // slab bytes
    constexpr bool FULLY= (RPB == H);
    constexpr int R0    = FULLY ? 1 : 0;
    constexpr int NR    = FULLY ? H : SR;
    constexpr int UPC   = HIN ? (CIN / 8) : 1;    // staging units per position
    constexpr int NU    = NR * H * UPC;
    constexpr int ITERS = (NU + BDIM - 1) / BDIM;
    constexpr bool GUARD= !(FULLY && (NU % BDIM == 0));

    __shared__ alignas(16) char slab[2][SLABB];

    const int tid = threadIdx.x;
    const int G = gridDim.x, bx = blockIdx.x;
    const int pb = (bx & 7) * (G >> 3) + (bx >> 3);   // XCD clustering (b -> b>>2)
    const int cgb   = pb % CGRP;
    const int strip = (pb / CGRP) % STRIPS;
    const int b     = pb / (CGRP * STRIPS);

    const int wid = tid >> 6, l = tid & 63;
    const int seg = wid / NWps;
    const int wlv = wid % NWps;
    const int xw = wlv % XW, yw = wlv / XW;
    const int xl = l % WX, ylw = l / WX;
    const int x  = xw * WX + xl;
    const int yy = yw * WY + ylw;
    const int y0 = strip * RPB;
    const int y  = y0 + yy;

    const int c0 = __builtin_amdgcn_readfirstlane((cgb * SEGS + seg) * CG);
    const float* __restrict__ wu = w + (size_t)c0 * (CIN * 9);

    // patch base byte offsets
    int addrB[9];
    #pragma unroll
    for (int dr = 0; dr < 3; ++dr)
        #pragma unroll
        for (int dc = 0; dc < 3; ++dc)
            addrB[dr * 3 + dc] = ((yy + dr) * COLS + (x + dc)) * PSB;

    // staging maps (lane-invariant over t). HIN: unit = 16B of 8 channels at
    // one position (contiguous in HWC global). f32: unit = 2 floats (2 planes).
    int goff[ITERS], loffB[ITERS];
    #pragma unroll
    for (int i = 0; i < ITERS; ++i) {
        const int idx = tid + i * BDIM;
        int j, gx, rr0;
        if constexpr (HIN) { j = idx % UPC; gx = (idx / UPC) % H; rr0 = idx / (UPC * H); }
        else               { j = 0;         gx = idx % H;         rr0 = (idx / H) % NR; }
        const int rr = R0 + rr0;
        const int gy = y0 - 1 + rr;
        const bool ok = (idx < NU) && ((unsigned)gy < (unsigned)H);
        if constexpr (HIN) goff[i] = ok ? ((gy * H + gx) * UPC + j) : -1;
        else               goff[i] = ok ? (gy * H + gx) : -1;
        loffB[i] = ok ? ((rr * COLS + (gx + 1)) * PSB + 16 * j) : -1;
    }

    constexpr bool WREG = !HIN && (CG * CIN * 9) <= 80;   // L0 only
    float wreg[WREG ? (CG * CIN * 9) : 1];
    if constexpr (WREG) {
        #pragma unroll
        for (int i = 0; i < CG * CIN * 9; ++i) wreg[i] = wu[i];
    }

    // zero both slabs (halo rows/cols persist as zeros)
    for (int i = tid; i < (2 * SLABB) / 4; i += BDIM) ((int*)slab)[i] = 0;
    __syncthreads();

    float vmem[CG];
    #pragma unroll
    for (int c = 0; c < CG; ++c) vmem[c] = 0.f;

    f4 pf[ITERS];
    #define GATHER(t_)                                                            \
        if constexpr (HIN) {                                                      \
            const f4* inb = (const f4*)in_ + (size_t)(b * T + (t_)) * (HH * UPC); \
            _Pragma("unroll")                                                     \
            for (int i = 0; i < ITERS; ++i) {                                     \
                f4 r_ = {0.f, 0.f, 0.f, 0.f};                                     \
                if (!GUARD || goff[i] >= 0) r_ = inb[goff[i]];                    \
                pf[i] = r_;                                                       \
            }                                                                     \
        } else {                                                                  \
            const float* inb = (const float*)in_ + (size_t)(b * T + (t_)) * (CIN * HH); \
            _Pragma("unroll")                                                     \
            for (int i = 0; i < ITERS; ++i) {                                     \
                f4 r_ = {0.f, 0.f, 0.f, 0.f};                                     \
                if (goff[i] >= 0) { r_.x = inb[goff[i]]; r_.y = inb[goff[i] + HH]; } \
                pf[i] = r_;                                                       \
            }                                                                     \
        }
    #define STAGE(buf)                                                            \
        _Pragma("unroll")                                                         \
        for (int i = 0; i < ITERS; ++i) {                                         \
            if (!GUARD || loffB[i] >= 0) {                                        \
                if constexpr (HIN) *(f4*)(&slab[buf][loffB[i]]) = pf[i];          \
                else { f2 v2_; v2_.x = pf[i].x; v2_.y = pf[i].y;                  \
                       *(f2*)(&slab[buf][loffB[i]]) = v2_; }                      \
            }                                                                     \
        }

    {   // prologue: stage frame 0, prefetch frame 1
        GATHER(0)
        STAGE(0)
        GATHER(1)
    }
    __syncthreads();

    for (int t = 0; t < T; ++t) {
        if (t + 1 < T) { STAGE((t + 1) & 1) }
        if (t + 2 < T) { GATHER(t + 2) }

        const char* sb = slab[t & 1];
        float acc[CG];
        #pragma unroll
        for (int c = 0; c < CG; ++c) acc[c] = 0.f;

        if constexpr (HIN) {
            #pragma unroll
            for (int o = 0; o < CIN / 8; ++o) {
                h8 P[9];
                #pragma unroll
                for (int k = 0; k < 9; ++k)
                    P[k] = *(const h8*)(sb + addrB[k] + 16 * o);
                #pragma unroll
                for (int cid = 0; cid < 8; ++cid) {
                    const int ci = 8 * o + cid;
                    #pragma unroll
                    for (int c = 0; c < CG; ++c)
                        #pragma unroll
                        for (int k = 0; k < 9; ++k)
                            acc[c] = fmaf((float)P[k][cid],
                                          wu[(size_t)(c * CIN + ci) * 9 + k], acc[c]);
                }
            }
        } else {
            f2 P[9];
            #pragma unroll
            for (int k = 0; k < 9; ++k)
                P[k] = *(const f2*)(sb + addrB[k]);
            #pragma unroll
            for (int cid = 0; cid < 2; ++cid)
                #pragma unroll
                for (int c = 0; c < CG; ++c)
                    #pragma unroll
                    for (int k = 0; k < 9; ++k)
                        acc[c] = fmaf(P[k][cid],
                                      WREG ? wreg[(c * CIN + cid) * 9 + k]
                                           : wu[(size_t)(c * CIN + cid) * 9 + k],
                                      acc[c]);
        }

        float sv[CG];
        #pragma unroll
        for (int c = 0; c < CG; ++c) {
            vmem[c] += acc[c];
            float s = (vmem[c] >= THRESH) ? 1.f : 0.f;
            vmem[c] -= THRESH * s;
            float sum = s;                         // exact 0/1 sums
            sum += __shfl_xor(sum, 1);             // (s0+s1)
            sum += __shfl_xor(sum, WX);            // + (s2+s3)
            sv[c] = 0.25f * sum;                   // in {0,.25,.5,.75,1} — exact f16
        }
        if (((xl | ylw) & 1) == 0) {
            const size_t ob = ((size_t)(b * T + t) * PP + (y >> 1) * Hp + (x >> 1)) * COUT + c0;
            if constexpr (CG == 4) {
                h4 hv = {(_Float16)sv[0], (_Float16)sv[1], (_Float16)sv[2], (_Float16)sv[3]};
                *(h4*)(out + ob) = hv;
            } else if constexpr (CG == 2) {
                h2 hv = {(_Float16)sv[0], (_Float16)sv[1]};
                *(h2*)(out + ob) = hv;
            } else {
                out[ob] = (_Float16)sv[0];
            }
        }
        __syncthreads();                           // single barrier per timestep
    }
    #undef GATHER
    #undef STAGE
}

// ---------------------------------------------------------------------------
// Linear: out (1600, 11) = h (1600, 1024 f16 HWC) @ wl_perm^T (11, 1024)
// ---------------------------------------------------------------------------
__global__ void linear_kernel(const _Float16* __restrict__ h, const float* __restrict__ w,
                              float* __restrict__ out) {
    __shared__ float hs[1024];
    __shared__ float part[16][17];
    const int n = blockIdx.x;
    for (int i = threadIdx.x; i < 1024; i += blockDim.x)
        hs[i] = (float)h[(size_t)n * 1024 + i];
    __syncthreads();
    const int j = threadIdx.x & 15, ch = threadIdx.x >> 4;
    float acc = 0.f;
    if (j < 11) {
        const float* wr = w + (size_t)j * 1024 + ch * 64;
        const float* hh = hs + ch * 64;
        #pragma unroll 8
        for (int k = 0; k < 64; ++k) acc = fmaf(hh[k], wr[k], acc);
    }
    part[j][ch] = acc;
    __syncthreads();
    if (threadIdx.x < 11) {
        float s = 0.f;
        #pragma unroll
        for (int cc = 0; cc < 16; ++cc) s += part[threadIdx.x][cc];
        out[(size_t)n * 11 + threadIdx.x] = s;
    }
}

// ---------------------------------------------------------------------------
extern "C" void kernel_launch(void* const* d_in, const int* in_sizes, int n_in,
                              void* d_out, int out_size, void* d_ws, size_t ws_size,
                              hipStream_t stream) {
    const int B = 32, T = 50;

    const float* x   = (const float*)d_in[0];
    const float* c0v = (const float*)d_in[1];
    const float* c0g = (const float*)d_in[2];
    const float* c1v = (const float*)d_in[3];
    const float* c1g = (const float*)d_in[4];
    const float* c2v = (const float*)d_in[5];
    const float* c2g = (const float*)d_in[6];
    const float* c3v = (const float*)d_in[7];
    const float* c3g = (const float*)d_in[8];
    const float* lv  = (const float*)d_in[9];
    const float* lg  = (const float*)d_in[10];
    float* out = (float*)d_out;

    // Workspace layout
    float* ws = (float*)d_ws;
    float* w0 = ws;                    // 8*2*9     = 144
    float* w1 = w0 + 144;              // 16*8*9    = 1152
    float* w2 = w1 + 1152;             // 32*16*9   = 4608
    float* w3 = w2 + 4608;             // 64*32*9   = 18432
    float* wl = w3 + 18432;            // 11*1024   = 11264 (HWC-permuted)
    _Float16* bufA16 = (_Float16*)(ws + 40960);            // L0 out f16 HWC (13.1M halves)
    _Float16* bufB16 = (_Float16*)(ws + 40960 + 13107200); // L1 out f16 HWC (6.55M halves)
    // L2 out reuses bufA16; L3 out reuses bufB16.

    wnorm_all<<<131, 64, 0, stream>>>(c0v, c0g, c1v, c1g, c2v, c2g, c3v, c3g,
                                      lv, lg, w0, w1, w2, w3, wl);

    // <CIN,H,COUT,CG,WX,SEGS,BDIM,PSB>  grid = B * CGRP * STRIPS
    conv_iaf_pool<2,  64, 8,  4, 32, 1, 256, 8 ><<<1024, 256, 0, stream>>>(x,       w0, bufA16, B, T); // L0
    conv_iaf_pool<8,  32, 16, 4, 32, 1, 256, 16><<<512,  256, 0, stream>>>(bufA16,  w1, bufB16, B, T); // L1
    conv_iaf_pool<16, 16, 32, 2, 16, 2, 256, 48><<<512,  256, 0, stream>>>(bufB16,  w2, bufA16, B, T); // L2
    conv_iaf_pool<32, 8,  64, 1, 8,  4, 256, 80><<<512,  256, 0, stream>>>(bufA16,  w3, bufB16, B, T); // L3

    linear_kernel<<<B * T, 256, 0, stream>>>(bufB16, wl, out);
}